// Round 6
// baseline (957.687 us; speedup 1.0000x reference)
//
#include <hip/hip_runtime.h>

#define E_N 100000
#define NTOT 84000
#define NDST 234000   // concatenated per-type dst index space

typedef __attribute__((ext_vector_type(8))) short bfrag8;
typedef __attribute__((ext_vector_type(4))) float accf4;

__device__ __forceinline__ void atomAddF(float* p, float v) {
    unsafeAtomicAdd(p, v);
}

__device__ __forceinline__ float lrelu(float v) { return v >= 0.f ? v : 0.2f * v; }

// fp32 -> bf16 round-to-nearest-even, and back
__device__ __forceinline__ unsigned short f2bf(float f) {
    unsigned u = __float_as_uint(f);
    return (unsigned short)((u + 0x7FFFu + ((u >> 16) & 1u)) >> 16);
}
__device__ __forceinline__ float bf2f(unsigned short h) {
    return __uint_as_float(((unsigned)h) << 16);
}
// packed x element: low 16 = hi bf16, high 16 = lo bf16 (hi+lo == fp32 value to 2^-18)
__device__ __forceinline__ unsigned packf(float o) {
    unsigned short h = f2bf(o);
    unsigned short l = f2bf(o - bf2f(h));
    return (unsigned)h | ((unsigned)l << 16);
}
__device__ __forceinline__ float unpk(unsigned u) {
    return __uint_as_float(u << 16) + __uint_as_float(u & 0xffff0000u);
}

// CSR dst-space bases per edge type t
__constant__ int c_tbase[8] = {0, 1000, 51000, 71000, 121000, 126000, 176000, 184000};

struct EI8 { const int* p[8]; };

// ---------------- weight pre-split: W[K][256] fp32 -> BThi/BTlo[256][K] bf16 ----------
struct BTJob { const float* W; unsigned short* hi; unsigned short* lo; int K; int kshift; };
struct BTBatch { BTJob j[17]; };

__global__ __launch_bounds__(256) void makeBT(BTBatch b)
{
    BTJob jb = b.j[blockIdx.z];
    int idx = blockIdx.x * 256 + threadIdx.x;   // n*K + k
    if (idx >= (jb.K << 8)) return;
    int n = idx >> jb.kshift;
    int k = idx & (jb.K - 1);
    float w = jb.W[(size_t)k * 256 + n];
    unsigned short h = f2bf(w);
    jb.hi[idx] = h;
    jb.lo[idx] = f2bf(w - bf2f(h));
}

// ---------------- MFMA split-bf16 GEMM ------------------------------------------------
// C[M x 256] = A[M x K] @ B[K x 256]; 128x128 tile (grid.y=2), 4 waves 2x2 quadrants,
// 4x4 MFMA 16x16x32 tiles each. acc += Ahi*B1 + Alo*B1 + Ahi*B2.
// A is either packed-uint (hi|lo<<16) or raw fp32 (af32). LDS XOR-swizzled, stride 32.
struct MJob { const void* A; const unsigned short* BThi; const unsigned short* BTlo;
              unsigned* Cp; unsigned short* Cbf; const float* bias; int M; int K; int relu; int af32; };
struct MBatch { MJob j[8]; };

__global__ __launch_bounds__(256, 4) void gemm_mfma(MBatch batch)
{
    const MJob jb = batch.j[blockIdx.z];
    const int bm = blockIdx.x * 128;
    if (bm >= jb.M) return;
    const int bn = blockIdx.y * 128;
    const int M = jb.M, K = jb.K;

    __shared__ unsigned short Ah[128 * 32];
    __shared__ unsigned short Al[128 * 32];
    __shared__ unsigned short B1[128 * 32];
    __shared__ unsigned short B2[128 * 32];

    const int tid  = threadIdx.x;
    const int wv   = tid >> 6;
    const int lane = tid & 63;
    const int qr = wv >> 1, qc = wv & 1;
    const int lm = lane & 15;
    const int lq = lane >> 4;

    accf4 acc[4][4] = {};   // [mt][nt]

    for (int k0 = 0; k0 < K; k0 += 32) {
        // ---- stage A: 128 rows x 32 elems, deinterleave packed (or split fp32) ----
#pragma unroll
        for (int it = 0; it < 4; ++it) {
            int slot = it * 256 + tid;       // 0..1023
            int m  = slot >> 3;              // 0..127
            int kq = (slot & 7) << 2;        // 0,4,...,28
            unsigned h01, h23, l01, l23;
            if (jb.af32) {
                float4 v = make_float4(0.f, 0.f, 0.f, 0.f);
                if (bm + m < M) v = *(const float4*)((const float*)jb.A + (size_t)(bm + m) * K + k0 + kq);
                unsigned short h0 = f2bf(v.x), h1 = f2bf(v.y), h2 = f2bf(v.z), h3 = f2bf(v.w);
                unsigned short l0 = f2bf(v.x - bf2f(h0)), l1 = f2bf(v.y - bf2f(h1));
                unsigned short l2 = f2bf(v.z - bf2f(h2)), l3 = f2bf(v.w - bf2f(h3));
                h01 = (unsigned)h0 | ((unsigned)h1 << 16); h23 = (unsigned)h2 | ((unsigned)h3 << 16);
                l01 = (unsigned)l0 | ((unsigned)l1 << 16); l23 = (unsigned)l2 | ((unsigned)l3 << 16);
            } else {
                uint4 v = make_uint4(0u, 0u, 0u, 0u);
                if (bm + m < M) v = *(const uint4*)((const unsigned*)jb.A + (size_t)(bm + m) * K + k0 + kq);
                h01 = (v.x & 0xffffu) | (v.y << 16);
                h23 = (v.z & 0xffffu) | (v.w << 16);
                l01 = (v.x >> 16) | (v.y & 0xffff0000u);
                l23 = (v.z >> 16) | (v.w & 0xffff0000u);
            }
            int g = kq >> 3, half = (kq >> 2) & 1;
            int off = m * 32 + ((g ^ (m & 3)) << 3) + half * 4;   // shorts
            uint2 hw; hw.x = h01; hw.y = h23;
            uint2 lw; lw.x = l01; lw.y = l23;
            *(uint2*)&Ah[off] = hw;
            *(uint2*)&Al[off] = lw;
        }
        // ---- stage B: 128 n-rows x 32 k, both panels ----
#pragma unroll
        for (int it = 0; it < 2; ++it) {
            int slot = it * 256 + tid;       // 0..511
            int n = slot >> 2;               // 0..127
            int g = slot & 3;                // k-granule
            size_t go = (size_t)(bn + n) * K + k0 + g * 8;
            int off = n * 32 + ((g ^ (n & 3)) << 3);
            *(uint4*)&B1[off] = *(const uint4*)(jb.BThi + go);
            *(uint4*)&B2[off] = *(const uint4*)(jb.BTlo + go);
        }
        __syncthreads();

        bfrag8 ah[4], al[4], b1[4], b2[4];
#pragma unroll
        for (int t = 0; t < 4; ++t) {
            int am  = qr * 64 + t * 16 + lm;
            int bnn = qc * 64 + t * 16 + lm;
            ah[t] = *(const bfrag8*)&Ah[am * 32 + ((lq ^ (am & 3)) << 3)];
            al[t] = *(const bfrag8*)&Al[am * 32 + ((lq ^ (am & 3)) << 3)];
            b1[t] = *(const bfrag8*)&B1[bnn * 32 + ((lq ^ (bnn & 3)) << 3)];
            b2[t] = *(const bfrag8*)&B2[bnn * 32 + ((lq ^ (bnn & 3)) << 3)];
        }
#pragma unroll
        for (int mt = 0; mt < 4; ++mt)
#pragma unroll
            for (int nt = 0; nt < 4; ++nt) {
                acc[mt][nt] = __builtin_amdgcn_mfma_f32_16x16x32_bf16(ah[mt], b1[nt], acc[mt][nt], 0, 0, 0);
                acc[mt][nt] = __builtin_amdgcn_mfma_f32_16x16x32_bf16(al[mt], b1[nt], acc[mt][nt], 0, 0, 0);
                acc[mt][nt] = __builtin_amdgcn_mfma_f32_16x16x32_bf16(ah[mt], b2[nt], acc[mt][nt], 0, 0, 0);
            }
        __syncthreads();
    }

    // ---- epilogue: C/D layout col=lane&15, row=(lane>>4)*4+r ----
#pragma unroll
    for (int nt = 0; nt < 4; ++nt) {
        int col = bn + qc * 64 + nt * 16 + lm;
        float bv = jb.bias ? jb.bias[col] : 0.f;
#pragma unroll
        for (int mt = 0; mt < 4; ++mt) {
            int row0 = bm + qr * 64 + mt * 16 + lq * 4;
#pragma unroll
            for (int r = 0; r < 4; ++r) {
                int row = row0 + r;
                if (row < M) {
                    float o = acc[mt][nt][r] + bv;
                    if (jb.relu) o = fmaxf(o, 0.f);
                    if (jb.Cp)  jb.Cp[(size_t)row * 256 + col] = packf(o);
                    if (jb.Cbf) jb.Cbf[(size_t)row * 256 + col] = f2bf(o);
                }
            }
        }
    }
}

// ---------------- effective attention-projection matrices ----------------
__global__ __launch_bounds__(256) void fill_weff(const float* __restrict__ Wsrc,
                                                 const float* __restrict__ Wdst,
                                                 const float* __restrict__ asrc,
                                                 const float* __restrict__ adst,
                                                 float* __restrict__ weff)
{
    int idx = blockIdx.x * 256 + threadIdx.x;
    if (idx >= 81920) return;
    int col = idx & 31;
    int k   = (idx >> 5) & 255;
    int lnt = idx >> 13;
    int nt  = lnt % 5;
    int l   = lnt / 5;
    bool is_src; int t, h;
    if (nt == 0) {
        if (col < 16) { is_src = true;  t = (col >> 2) * 2;            h = col & 3; }
        else          { is_src = false; t = ((col - 16) >> 2) * 2 + 1; h = col & 3; }
    } else {
        if (col < 4)      { is_src = true;  t = 2 * nt - 1; h = col; }
        else if (col < 8) { is_src = false; t = 2 * nt - 2; h = col - 4; }
        else { weff[idx] = 0.f; return; }
    }
    const float* W = (is_src ? Wsrc : Wdst) + ((size_t)((l * 8 + t) * 256 + k)) * 256 + h * 64;
    const float* a = (is_src ? asrc : adst) + ((size_t)((l * 8 + t) * 4 + h)) * 64;
    float val = 0.f;
    for (int c = 0; c < 64; c++) val += W[c] * a[c];
    weff[idx] = val;
}

// ---------------- attn projections (packed-x input) ----------------
template<int NO>
__device__ __forceinline__ void attnproj_body(const unsigned* __restrict__ xrow,
                                              const float* __restrict__ W,
                                              float* __restrict__ out)
{
    float acc[NO];
#pragma unroll
    for (int j = 0; j < NO; j++) acc[j] = 0.f;
    for (int k = 0; k < 256; k += 4) {
        const uint4 xv = *(const uint4*)(xrow + k);
        float x0 = unpk(xv.x), x1 = unpk(xv.y), x2 = unpk(xv.z), x3 = unpk(xv.w);
#pragma unroll
        for (int j = 0; j < NO; j++) {
            acc[j] += x0 * W[(k + 0) * 32 + j] + x1 * W[(k + 1) * 32 + j]
                    + x2 * W[(k + 2) * 32 + j] + x3 * W[(k + 3) * 32 + j];
        }
    }
#pragma unroll
    for (int j = 0; j < NO; j++) out[j] = acc[j];
}

__global__ __launch_bounds__(256) void attnproj(const unsigned* __restrict__ x,
                                                const float* __restrict__ weff_l,
                                                float* __restrict__ attnT,
                                                float* __restrict__ attnC)
{
    int n = blockIdx.x * 256 + threadIdx.x;
    if (n >= NTOT) return;
    if (n < 50000) {
        attnproj_body<32>(x + (size_t)n * 256, weff_l, attnT + (size_t)n * 32);
    } else {
        int nt = (n < 51000) ? 1 : (n < 71000) ? 2 : (n < 76000) ? 3 : 4;
        attnproj_body<8>(x + (size_t)n * 256, weff_l + nt * 8192, attnC + (size_t)(n - 50000) * 8);
    }
}

// ---------------- CSR build ----------------
__global__ __launch_bounds__(256) void count_k(EI8 ei, int* __restrict__ cnt)
{
    int g = blockIdx.x * 256 + threadIdx.x;
    if (g >= 8 * E_N) return;
    int t = g / E_N;
    int i = g - t * E_N;
    int d = ei.p[t][E_N + i];
    atomicAdd(&cnt[c_tbase[t] + d], 1);
}

__global__ __launch_bounds__(256) void scanA(const int* __restrict__ cnt,
                                             int* __restrict__ rowptr,
                                             int* __restrict__ bsum)
{
    __shared__ int sd[256];
    int b = blockIdx.x, t = threadIdx.x;
    int base = b * 1024 + t * 4;
    int v0 = 0, v1 = 0, v2 = 0, v3 = 0;
    if (base + 0 < NDST) v0 = cnt[base + 0];
    if (base + 1 < NDST) v1 = cnt[base + 1];
    if (base + 2 < NDST) v2 = cnt[base + 2];
    if (base + 3 < NDST) v3 = cnt[base + 3];
    int s = v0 + v1 + v2 + v3;
    sd[t] = s;
    __syncthreads();
    for (int off = 1; off < 256; off <<= 1) {
        int x = 0;
        if (t >= off) x = sd[t - off];
        __syncthreads();
        if (t >= off) sd[t] += x;
        __syncthreads();
    }
    int run = sd[t] - s;
    if (t == 255) bsum[b] = sd[255];
    if (base + 0 < NDST) rowptr[base + 0] = run;          run += v0;
    if (base + 1 < NDST) rowptr[base + 1] = run;          run += v1;
    if (base + 2 < NDST) rowptr[base + 2] = run;          run += v2;
    if (base + 3 < NDST) rowptr[base + 3] = run;
}

__global__ __launch_bounds__(256) void scanB(int* __restrict__ bsum, int nb)
{
    __shared__ int sd[256];
    int t = threadIdx.x;
    int v = (t < nb) ? bsum[t] : 0;
    sd[t] = v;
    __syncthreads();
    for (int off = 1; off < 256; off <<= 1) {
        int x = 0;
        if (t >= off) x = sd[t - off];
        __syncthreads();
        if (t >= off) sd[t] += x;
        __syncthreads();
    }
    if (t < nb) bsum[t] = sd[t] - v;
}

__global__ __launch_bounds__(256) void scanC(int* __restrict__ rowptr,
                                             const int* __restrict__ bsum,
                                             int* __restrict__ cursor)
{
    int b = blockIdx.x, t = threadIdx.x;
    int off = bsum[b];
    int base = b * 1024 + t * 4;
#pragma unroll
    for (int j = 0; j < 4; j++) {
        int i = base + j;
        if (i < NDST) {
            int r = rowptr[i] + off;
            rowptr[i] = r;
            cursor[i] = r;
        }
    }
    if (b == 0 && t == 0) rowptr[NDST] = 8 * E_N;
}

__global__ __launch_bounds__(256) void place_k(EI8 ei, int* __restrict__ cursor,
                                               int* __restrict__ ssrc)
{
    int g = blockIdx.x * 256 + threadIdx.x;
    if (g >= 8 * E_N) return;
    int t = g / E_N;
    int i = g - t * E_N;
    int d = ei.p[t][E_N + i];
    int s = ei.p[t][i];
    int pos = atomicAdd(&cursor[c_tbase[t] + d], 1);
    ssrc[pos] = s;
}

// ---------------- aggregate-first ts->compact: bf16 gather, unroll-4 -----------------
__global__ __launch_bounds__(256) void aggx_k(const float* __restrict__ attnT,
                                              const float* __restrict__ attnC,
                                              const unsigned short* __restrict__ xtsbf,
                                              const int* __restrict__ rowptr,
                                              const int* __restrict__ ssrc,
                                              unsigned* __restrict__ aggx)
{
    int w = blockIdx.x * 4 + (threadIdx.x >> 6);   // 0..33999 (grid 8500)
    int lane = threadIdx.x & 63;
    int h = lane >> 4;
    int ch = (h << 6) | ((lane & 15) << 2);
    int q, dloc;
    if (w < 1000)       { q = 0; dloc = w; }
    else if (w < 21000) { q = 1; dloc = w - 1000; }
    else if (w < 26000) { q = 2; dloc = w - 21000; }
    else                { q = 3; dloc = w - 26000; }
    const int csr4[4]  = {0, 51000, 121000, 176000};
    const int soff4[4] = {0, 4, 8, 12};
    int soff = soff4[q];
    int r0 = rowptr[csr4[q] + dloc], r1 = rowptr[csr4[q] + dloc + 1];
    float ed = attnC[(size_t)w * 8 + 4 + h];
    float den = 0.f, sx = 0.f, sy = 0.f, sz = 0.f, sw = 0.f;
    int e = r0;
    for (; e + 4 <= r1; e += 4) {
        int sA = ssrc[e], sB = ssrc[e + 1], sC = ssrc[e + 2], sD = ssrc[e + 3];
        float eA = attnT[(size_t)sA * 32 + soff + h];
        float eB = attnT[(size_t)sB * 32 + soff + h];
        float eC = attnT[(size_t)sC * 32 + soff + h];
        float eD = attnT[(size_t)sD * 32 + soff + h];
        ushort4 rA = *(const ushort4*)(xtsbf + (size_t)sA * 256 + ch);
        ushort4 rB = *(const ushort4*)(xtsbf + (size_t)sB * 256 + ch);
        ushort4 rC = *(const ushort4*)(xtsbf + (size_t)sC * 256 + ch);
        ushort4 rD = *(const ushort4*)(xtsbf + (size_t)sD * 256 + ch);
        float xA = __expf(lrelu(eA + ed));
        float xB = __expf(lrelu(eB + ed));
        float xC = __expf(lrelu(eC + ed));
        float xD = __expf(lrelu(eD + ed));
        den += (xA + xB) + (xC + xD);
        sx += xA * bf2f(rA.x) + xB * bf2f(rB.x) + xC * bf2f(rC.x) + xD * bf2f(rD.x);
        sy += xA * bf2f(rA.y) + xB * bf2f(rB.y) + xC * bf2f(rC.y) + xD * bf2f(rD.y);
        sz += xA * bf2f(rA.z) + xB * bf2f(rB.z) + xC * bf2f(rC.z) + xD * bf2f(rD.z);
        sw += xA * bf2f(rA.w) + xB * bf2f(rB.w) + xC * bf2f(rC.w) + xD * bf2f(rD.w);
    }
    for (; e < r1; e++) {
        int s = ssrc[e];
        float es = attnT[(size_t)s * 32 + soff + h];
        float ex = __expf(lrelu(es + ed));
        den += ex;
        ushort4 rv = *(const ushort4*)(xtsbf + (size_t)s * 256 + ch);
        sx += ex * bf2f(rv.x); sy += ex * bf2f(rv.y);
        sz += ex * bf2f(rv.z); sw += ex * bf2f(rv.w);
    }
    float inv = 1.f / (den + 1e-16f);
    uint4 o;
    o.x = packf(sx * inv); o.y = packf(sy * inv);
    o.z = packf(sz * inv); o.w = packf(sw * inv);
    *(uint4*)(aggx + (size_t)w * 256 + ch) = o;
}

// ---------------- fused compact->ts aggregation (L1): packed output ------------------
__global__ __launch_bounds__(256) void agg_ts(const float* __restrict__ attnT,
                                              const float* __restrict__ attnC,
                                              const unsigned short* __restrict__ hscbf,
                                              const int* __restrict__ rowptr,
                                              const int* __restrict__ ssrc,
                                              const float* __restrict__ bconv_l,
                                              unsigned* __restrict__ xout)
{
    int d = blockIdx.x * 4 + (threadIdx.x >> 6);   // grid 12500
    int lane = threadIdx.x & 63;
    int h = lane >> 4;
    int ch = (h << 6) | ((lane & 15) << 2);
    const int co4[4]   = {0, 1000, 21000, 26000};
    const int tb4[4]   = {1000, 71000, 126000, 184000};
    const int doff4[4] = {16, 20, 24, 28};
    const int bo4[4]   = {256, 768, 1280, 1792};

    int r0q[4], nq[4]; float edq[4];
    int mx = 0;
#pragma unroll
    for (int q = 0; q < 4; q++) {
        int a = rowptr[tb4[q] + d], b = rowptr[tb4[q] + d + 1];
        r0q[q] = a; nq[q] = b - a;
        mx = max(mx, b - a);
        edq[q] = attnT[(size_t)d * 32 + doff4[q] + h];
    }
    float den[4] = {0.f, 0.f, 0.f, 0.f};
    float sx[4] = {0.f, 0.f, 0.f, 0.f}, sy[4] = {0.f, 0.f, 0.f, 0.f};
    float sz[4] = {0.f, 0.f, 0.f, 0.f}, sw[4] = {0.f, 0.f, 0.f, 0.f};
    for (int i = 0; i < mx; i++) {
#pragma unroll
        for (int q = 0; q < 4; q++) {
            if (i < nq[q]) {
                int s = ssrc[r0q[q] + i];
                float es = attnC[(size_t)(co4[q] + s) * 8 + h];
                float ex = __expf(lrelu(es + edq[q]));
                den[q] += ex;
                ushort4 hv = *(const ushort4*)(hscbf + (size_t)(co4[q] + s) * 256 + ch);
                sx[q] += ex * bf2f(hv.x); sy[q] += ex * bf2f(hv.y);
                sz[q] += ex * bf2f(hv.z); sw[q] += ex * bf2f(hv.w);
            }
        }
    }
    float ax = 0.f, ay = 0.f, az = 0.f, aw = 0.f;
#pragma unroll
    for (int q = 0; q < 4; q++) {
        const float* b = bconv_l + bo4[q] + ch;
        float inv = 1.f / (den[q] + 1e-16f);
        ax += b[0] + sx[q] * inv; ay += b[1] + sy[q] * inv;
        az += b[2] + sz[q] * inv; aw += b[3] + sw[q] * inv;
    }
    uint4 o;
    o.x = packf(fmaxf(ax, 0.f)); o.y = packf(fmaxf(ay, 0.f));
    o.z = packf(fmaxf(az, 0.f)); o.w = packf(fmaxf(aw, 0.f));
    *(uint4*)(xout + (size_t)d * 256 + ch) = o;
}

// ---------------- L2 variant: aggregate + fused mean-pool column sums ----------------
__global__ __launch_bounds__(256) void agg_tsum(const float* __restrict__ attnT,
                                                const float* __restrict__ attnC,
                                                const unsigned short* __restrict__ hscbf,
                                                const int* __restrict__ rowptr,
                                                const int* __restrict__ ssrc,
                                                const float* __restrict__ bconv_l,
                                                float* __restrict__ gsum)
{
    int wv = threadIdx.x >> 6, lane = threadIdx.x & 63;
    int h = lane >> 4;
    int ch = (h << 6) | ((lane & 15) << 2);
    const int co4[4]   = {0, 1000, 21000, 26000};
    const int tb4[4]   = {1000, 71000, 126000, 184000};
    const int doff4[4] = {16, 20, 24, 28};
    const int bo4[4]   = {256, 768, 1280, 1792};
    float cs0 = 0.f, cs1 = 0.f, cs2 = 0.f, cs3 = 0.f;

    for (int i8 = 0; i8 < 8; ++i8) {
        int d = (blockIdx.x * 4 + wv) * 8 + i8;
        if (d >= 50000) break;
        int r0q[4], nq[4]; float edq[4];
        int mx = 0;
#pragma unroll
        for (int q = 0; q < 4; q++) {
            int a = rowptr[tb4[q] + d], b = rowptr[tb4[q] + d + 1];
            r0q[q] = a; nq[q] = b - a;
            mx = max(mx, b - a);
            edq[q] = attnT[(size_t)d * 32 + doff4[q] + h];
        }
        float den[4] = {0.f, 0.f, 0.f, 0.f};
        float sx[4] = {0.f, 0.f, 0.f, 0.f}, sy[4] = {0.f, 0.f, 0.f, 0.f};
        float sz[4] = {0.f, 0.f, 0.f, 0.f}, sw[4] = {0.f, 0.f, 0.f, 0.f};
        for (int i = 0; i < mx; i++) {
#pragma unroll
            for (int q = 0; q < 4; q++) {
                if (i < nq[q]) {
                    int s = ssrc[r0q[q] + i];
                    float es = attnC[(size_t)(co4[q] + s) * 8 + h];
                    float ex = __expf(lrelu(es + edq[q]));
                    den[q] += ex;
                    ushort4 hv = *(const ushort4*)(hscbf + (size_t)(co4[q] + s) * 256 + ch);
                    sx[q] += ex * bf2f(hv.x); sy[q] += ex * bf2f(hv.y);
                    sz[q] += ex * bf2f(hv.z); sw[q] += ex * bf2f(hv.w);
                }
            }
        }
        float ax = 0.f, ay = 0.f, az = 0.f, aw = 0.f;
#pragma unroll
        for (int q = 0; q < 4; q++) {
            const float* b = bconv_l + bo4[q] + ch;
            float inv = 1.f / (den[q] + 1e-16f);
            ax += b[0] + sx[q] * inv; ay += b[1] + sy[q] * inv;
            az += b[2] + sz[q] * inv; aw += b[3] + sw[q] * inv;
        }
        cs0 += fmaxf(ax, 0.f); cs1 += fmaxf(ay, 0.f);
        cs2 += fmaxf(az, 0.f); cs3 += fmaxf(aw, 0.f);
    }

    __shared__ float4 red4[256];
    float4 cv; cv.x = cs0; cv.y = cs1; cv.z = cs2; cv.w = cs3;
    red4[threadIdx.x] = cv;
    __syncthreads();
    if (threadIdx.x < 64) {
        float4 a = red4[threadIdx.x], b = red4[threadIdx.x + 64];
        float4 c = red4[threadIdx.x + 128], dd = red4[threadIdx.x + 192];
        int cch = ((threadIdx.x >> 4) << 6) | ((threadIdx.x & 15) << 2);
        atomAddF(gsum + cch + 0, a.x + b.x + c.x + dd.x);
        atomAddF(gsum + cch + 1, a.y + b.y + c.y + dd.y);
        atomAddF(gsum + cch + 2, a.z + b.z + c.z + dd.z);
        atomAddF(gsum + cch + 3, a.w + b.w + c.w + dd.w);
    }
}

// ---------------- head ----------------
__global__ __launch_bounds__(128) void head_k(const float* __restrict__ gsum,
                                              const float* __restrict__ Wc1,
                                              const float* __restrict__ bc1,
                                              const float* __restrict__ Wc2,
                                              const float* __restrict__ bc2,
                                              float* __restrict__ out)
{
    __shared__ float g[256];
    __shared__ float red[128];
    int t = threadIdx.x;
    g[t] = gsum[t] * (1.f / 50000.f);
    g[t + 128] = gsum[t + 128] * (1.f / 50000.f);
    __syncthreads();
    float acc = bc1[t];
    for (int k = 0; k < 256; k++) acc += g[k] * Wc1[k * 128 + t];
    red[t] = fmaxf(acc, 0.f) * Wc2[t];
    __syncthreads();
    for (int sft = 64; sft > 0; sft >>= 1) {
        if (t < sft) red[t] += red[t + sft];
        __syncthreads();
    }
    if (t == 0) out[0] = red[0] + bc2[0];
}

extern "C" void kernel_launch(void* const* d_in, const int* in_sizes, int n_in,
                              void* d_out, int out_size, void* d_ws, size_t ws_size,
                              hipStream_t stream)
{
    const float* ts_x   = (const float*)d_in[0];
    const float* emb[4] = {(const float*)d_in[1], (const float*)d_in[2],
                           (const float*)d_in[3], (const float*)d_in[4]};
    const float* Wp_ts  = (const float*)d_in[5];
    const float* bp_ts  = (const float*)d_in[6];
    const float* Wp_c   = (const float*)d_in[7];
    const float* bp_c   = (const float*)d_in[8];
    const float* Wsrc   = (const float*)d_in[9];
    const float* Wdst   = (const float*)d_in[10];
    const float* asrc   = (const float*)d_in[11];
    const float* adst   = (const float*)d_in[12];
    const float* bconv  = (const float*)d_in[13];
    const float* Wc1    = (const float*)d_in[14];
    const float* bc1    = (const float*)d_in[15];
    const float* Wc2    = (const float*)d_in[16];
    const float* bc2    = (const float*)d_in[17];
    EI8 ei;
    for (int t = 0; t < 8; t++) ei.p[t] = (const int*)d_in[18 + t];

    // workspace layout (4-byte units)
    unsigned* x0p  = (unsigned*)d_ws;       // 21,504,000
    unsigned* x1p  = x0p  + 21504000;       // 21,504,000 (ts region doubles as aggx in L1)
    float* attnT = (float*)(x1p + 21504000);// 1,600,000
    float* attnC = attnT + 1600000;         // 272,000
    float* weff  = attnC + 272000;          // 81,920
    float* gsum  = weff  + 81920;           // 256
    int* rowptr  = (int*)(gsum + 256);      // 234,004
    int* bsum    = rowptr + 234004;         // 256
    int* ssrc    = bsum + 256;              // 800,000
    unsigned short* xtsbf = (unsigned short*)(ssrc + 800000);   // 12,800,000 us
    unsigned short* hscbf = xtsbf + 12800000;                   //  8,704,000 us
    unsigned short* btp   = hscbf + 8704000;                    //  1,867,776 us
    int* cursor  = (int*)hscbf;             // alias: CSR build finishes before hscbf used
    unsigned* aggx = x1p;                   // alias ts region of x1p

    unsigned short* bt_ts_h = btp;
    unsigned short* bt_ts_l = bt_ts_h + 16384;
    unsigned short* bt_c_h[4], *bt_c_l[4];
    {
        unsigned short* p = bt_ts_l + 16384;
        for (int q = 0; q < 4; q++) { bt_c_h[q] = p; p += 32768; bt_c_l[q] = p; p += 32768; }
    }
    unsigned short* bt_w = bt_ts_l + 16384 + 8 * 32768;
    auto wpan_h = [&](int l, int t) { return bt_w + (size_t)((l == 0 ? t : 8 + t / 2) * 2) * 65536; };
    auto wpan_l = [&](int l, int t) { return wpan_h(l, t) + 65536; };

    // ---- CSR build ----
    hipMemsetAsync(cursor, 0, NDST * sizeof(int), stream);
    count_k<<<3125, 256, 0, stream>>>(ei, cursor);
    scanA<<<229, 256, 0, stream>>>(cursor, rowptr, bsum);
    scanB<<<1, 256, 0, stream>>>(bsum, 229);
    scanC<<<229, 256, 0, stream>>>(rowptr, bsum, cursor);
    place_k<<<3125, 256, 0, stream>>>(ei, cursor, ssrc);

    // ---- weight pre-split ----
    {
        BTBatch b = {};
        int zi = 0;
        b.j[zi++] = {Wp_ts, bt_ts_h, bt_ts_l, 64, 6};
        for (int q = 0; q < 4; q++)
            b.j[zi++] = {Wp_c + q * 32768, bt_c_h[q], bt_c_l[q], 128, 7};
        for (int t = 0; t < 8; t++)
            b.j[zi++] = {Wsrc + (size_t)(0 * 8 + t) * 65536, wpan_h(0, t), wpan_l(0, t), 256, 8};
        for (int t = 1; t < 8; t += 2)
            b.j[zi++] = {Wsrc + (size_t)(1 * 8 + t) * 65536, wpan_h(1, t), wpan_l(1, t), 256, 8};
        makeBT<<<dim3(256, 1, 17), 256, 0, stream>>>(b);
    }

    fill_weff<<<320, 256, 0, stream>>>(Wsrc, Wdst, asrc, adst, weff);

    static const int Nd4[4]    = {1000, 20000, 5000, 8000};
    static const int co4[4]    = {0, 1000, 21000, 26000};
    static const int dbase4[4] = {50000, 51000, 71000, 76000};
    static const int tsrc[4]   = {1, 3, 5, 7};
    static const int tdst[4]   = {0, 2, 4, 6};

    // ---- input projections (fp32 A path); ts job also writes bf16 hi shadow ----
    {
        MBatch b = {};
        b.j[0] = {ts_x, bt_ts_h, bt_ts_l, x0p, xtsbf, bp_ts, 50000, 64, 0, 1};
        for (int q = 0; q < 4; q++)
            b.j[1 + q] = {emb[q], bt_c_h[q], bt_c_l[q], x0p + (size_t)dbase4[q] * 256,
                          nullptr, bp_c + q * 256, Nd4[q], 128, 0, 1};
        gemm_mfma<<<dim3(391, 2, 5), 256, 0, stream>>>(b);
    }

    // ---- layer 1 ----
    attnproj<<<329, 256, 0, stream>>>(x0p, weff, attnT, attnC);
    aggx_k<<<8500, 256, 0, stream>>>(attnT, attnC, xtsbf, rowptr, ssrc, aggx);
    {
        MBatch b = {};
        for (int q = 0; q < 4; q++)
            b.j[q] = {x0p + (size_t)dbase4[q] * 256, wpan_h(0, tsrc[q]), wpan_l(0, tsrc[q]),
                      nullptr, hscbf + (size_t)co4[q] * 256, nullptr, Nd4[q], 256, 0, 0};
        for (int q = 0; q < 4; q++)
            b.j[4 + q] = {aggx + (size_t)co4[q] * 256, wpan_h(0, tdst[q]), wpan_l(0, tdst[q]),
                          x1p + (size_t)dbase4[q] * 256, nullptr, bconv + tdst[q] * 256, Nd4[q], 256, 1, 0};
        gemm_mfma<<<dim3(157, 2, 8), 256, 0, stream>>>(b);
    }
    agg_ts<<<12500, 256, 0, stream>>>(attnT, attnC, hscbf, rowptr, ssrc, bconv, x1p);

    // ---- layer 2 (ts outputs only, fused into mean-pool) ----
    attnproj<<<329, 256, 0, stream>>>(x1p, weff + 40960, attnT, attnC);
    {
        MBatch b = {};
        for (int q = 0; q < 4; q++)
            b.j[q] = {x1p + (size_t)dbase4[q] * 256, wpan_h(1, tsrc[q]), wpan_l(1, tsrc[q]),
                      nullptr, hscbf + (size_t)co4[q] * 256, nullptr, Nd4[q], 256, 0, 0};
        gemm_mfma<<<dim3(157, 2, 4), 256, 0, stream>>>(b);
    }
    hipMemsetAsync(gsum, 0, 256 * sizeof(float), stream);
    agg_tsum<<<1563, 256, 0, stream>>>(attnT, attnC, hscbf, rowptr, ssrc, bconv + 2048, gsum);

    head_k<<<1, 128, 0, stream>>>(gsum, Wc1, bc1, Wc2, bc2, (float*)d_out);
}

// Round 7
// 833.162 us; speedup vs baseline: 1.1495x; 1.1495x over previous
//
#include <hip/hip_runtime.h>

#define E_N 100000
#define NTOT 84000
#define NDST 234000   // concatenated per-type dst index space

typedef __attribute__((ext_vector_type(8))) short bfrag8;
typedef __attribute__((ext_vector_type(4))) float accf4;

__device__ __forceinline__ void atomAddF(float* p, float v) {
    unsafeAtomicAdd(p, v);
}

__device__ __forceinline__ float lrelu(float v) { return v >= 0.f ? v : 0.2f * v; }

// fp32 -> bf16 round-to-nearest-even, and back
__device__ __forceinline__ unsigned short f2bf(float f) {
    unsigned u = __float_as_uint(f);
    return (unsigned short)((u + 0x7FFFu + ((u >> 16) & 1u)) >> 16);
}
__device__ __forceinline__ float bf2f(unsigned short h) {
    return __uint_as_float(((unsigned)h) << 16);
}
// packed x element: low 16 = hi bf16, high 16 = lo bf16 (hi+lo == fp32 value to 2^-18)
__device__ __forceinline__ unsigned packf(float o) {
    unsigned short h = f2bf(o);
    unsigned short l = f2bf(o - bf2f(h));
    return (unsigned)h | ((unsigned)l << 16);
}
__device__ __forceinline__ float unpk(unsigned u) {
    return __uint_as_float(u << 16) + __uint_as_float(u & 0xffff0000u);
}

// CSR dst-space bases per edge type t
__constant__ int c_tbase[8] = {0, 1000, 51000, 71000, 121000, 126000, 176000, 184000};

struct EI8 { const int* p[8]; };

// ---------------- weight pre-split: W[K][256] fp32 -> BThi/BTlo[256][K] bf16 ----------
struct BTJob { const float* W; unsigned short* hi; unsigned short* lo; int K; int kshift; };
struct BTBatch { BTJob j[17]; };

__global__ __launch_bounds__(256) void makeBT(BTBatch b)
{
    BTJob jb = b.j[blockIdx.z];
    int idx = blockIdx.x * 256 + threadIdx.x;   // n*K + k
    if (idx >= (jb.K << 8)) return;
    int n = idx >> jb.kshift;
    int k = idx & (jb.K - 1);
    float w = jb.W[(size_t)k * 256 + n];
    unsigned short h = f2bf(w);
    jb.hi[idx] = h;
    jb.lo[idx] = f2bf(w - bf2f(h));
}

// ---------------- MFMA split-bf16 GEMM ------------------------------------------------
// C[M x 256] = A[M x K] @ B[K x 256]; 128x128 tile (grid.y=2), 4 waves 2x2 quadrants,
// 4x4 MFMA 16x16x32 tiles each. acc += Ahi*B1 + Alo*B1 + Ahi*B2.
// A is either packed-uint (hi|lo<<16) or raw fp32 (af32). LDS XOR-swizzled, stride 32.
struct MJob { const void* A; const unsigned short* BThi; const unsigned short* BTlo;
              unsigned* Cp; unsigned short* Cbf; const float* bias; int M; int K; int relu; int af32; };
struct MBatch { MJob j[8]; };

__global__ __launch_bounds__(256, 4) void gemm_mfma(MBatch batch)
{
    const MJob jb = batch.j[blockIdx.z];
    const int bm = blockIdx.x * 128;
    if (bm >= jb.M) return;
    const int bn = blockIdx.y * 128;
    const int M = jb.M, K = jb.K;

    __shared__ unsigned short Ah[128 * 32];
    __shared__ unsigned short Al[128 * 32];
    __shared__ unsigned short B1[128 * 32];
    __shared__ unsigned short B2[128 * 32];

    const int tid  = threadIdx.x;
    const int wv   = tid >> 6;
    const int lane = tid & 63;
    const int qr = wv >> 1, qc = wv & 1;
    const int lm = lane & 15;
    const int lq = lane >> 4;

    accf4 acc[4][4] = {};   // [mt][nt]

    for (int k0 = 0; k0 < K; k0 += 32) {
        // ---- stage A: 128 rows x 32 elems, deinterleave packed (or split fp32) ----
#pragma unroll
        for (int it = 0; it < 4; ++it) {
            int slot = it * 256 + tid;       // 0..1023
            int m  = slot >> 3;              // 0..127
            int kq = (slot & 7) << 2;        // 0,4,...,28
            unsigned h01, h23, l01, l23;
            if (jb.af32) {
                float4 v = make_float4(0.f, 0.f, 0.f, 0.f);
                if (bm + m < M) v = *(const float4*)((const float*)jb.A + (size_t)(bm + m) * K + k0 + kq);
                unsigned short h0 = f2bf(v.x), h1 = f2bf(v.y), h2 = f2bf(v.z), h3 = f2bf(v.w);
                unsigned short l0 = f2bf(v.x - bf2f(h0)), l1 = f2bf(v.y - bf2f(h1));
                unsigned short l2 = f2bf(v.z - bf2f(h2)), l3 = f2bf(v.w - bf2f(h3));
                h01 = (unsigned)h0 | ((unsigned)h1 << 16); h23 = (unsigned)h2 | ((unsigned)h3 << 16);
                l01 = (unsigned)l0 | ((unsigned)l1 << 16); l23 = (unsigned)l2 | ((unsigned)l3 << 16);
            } else {
                uint4 v = make_uint4(0u, 0u, 0u, 0u);
                if (bm + m < M) v = *(const uint4*)((const unsigned*)jb.A + (size_t)(bm + m) * K + k0 + kq);
                h01 = (v.x & 0xffffu) | (v.y << 16);
                h23 = (v.z & 0xffffu) | (v.w << 16);
                l01 = (v.x >> 16) | (v.y & 0xffff0000u);
                l23 = (v.z >> 16) | (v.w & 0xffff0000u);
            }
            int g = kq >> 3, half = (kq >> 2) & 1;
            int off = m * 32 + ((g ^ (m & 3)) << 3) + half * 4;   // shorts
            uint2 hw; hw.x = h01; hw.y = h23;
            uint2 lw; lw.x = l01; lw.y = l23;
            *(uint2*)&Ah[off] = hw;
            *(uint2*)&Al[off] = lw;
        }
        // ---- stage B: 128 n-rows x 32 k, both panels ----
#pragma unroll
        for (int it = 0; it < 2; ++it) {
            int slot = it * 256 + tid;       // 0..511
            int n = slot >> 2;               // 0..127
            int g = slot & 3;                // k-granule
            size_t go = (size_t)(bn + n) * K + k0 + g * 8;
            int off = n * 32 + ((g ^ (n & 3)) << 3);
            *(uint4*)&B1[off] = *(const uint4*)(jb.BThi + go);
            *(uint4*)&B2[off] = *(const uint4*)(jb.BTlo + go);
        }
        __syncthreads();

        bfrag8 ah[4], al[4], b1[4], b2[4];
#pragma unroll
        for (int t = 0; t < 4; ++t) {
            int am  = qr * 64 + t * 16 + lm;
            int bnn = qc * 64 + t * 16 + lm;
            ah[t] = *(const bfrag8*)&Ah[am * 32 + ((lq ^ (am & 3)) << 3)];
            al[t] = *(const bfrag8*)&Al[am * 32 + ((lq ^ (am & 3)) << 3)];
            b1[t] = *(const bfrag8*)&B1[bnn * 32 + ((lq ^ (bnn & 3)) << 3)];
            b2[t] = *(const bfrag8*)&B2[bnn * 32 + ((lq ^ (bnn & 3)) << 3)];
        }
#pragma unroll
        for (int mt = 0; mt < 4; ++mt)
#pragma unroll
            for (int nt = 0; nt < 4; ++nt) {
                acc[mt][nt] = __builtin_amdgcn_mfma_f32_16x16x32_bf16(ah[mt], b1[nt], acc[mt][nt], 0, 0, 0);
                acc[mt][nt] = __builtin_amdgcn_mfma_f32_16x16x32_bf16(al[mt], b1[nt], acc[mt][nt], 0, 0, 0);
                acc[mt][nt] = __builtin_amdgcn_mfma_f32_16x16x32_bf16(ah[mt], b2[nt], acc[mt][nt], 0, 0, 0);
            }
        __syncthreads();
    }

    // ---- epilogue: C/D layout col=lane&15, row=(lane>>4)*4+r ----
#pragma unroll
    for (int nt = 0; nt < 4; ++nt) {
        int col = bn + qc * 64 + nt * 16 + lm;
        float bv = jb.bias ? jb.bias[col] : 0.f;
#pragma unroll
        for (int mt = 0; mt < 4; ++mt) {
            int row0 = bm + qr * 64 + mt * 16 + lq * 4;
#pragma unroll
            for (int r = 0; r < 4; ++r) {
                int row = row0 + r;
                if (row < M) {
                    float o = acc[mt][nt][r] + bv;
                    if (jb.relu) o = fmaxf(o, 0.f);
                    if (jb.Cp)  jb.Cp[(size_t)row * 256 + col] = packf(o);
                    if (jb.Cbf) jb.Cbf[(size_t)row * 256 + col] = f2bf(o);
                }
            }
        }
    }
}

// ---------------- effective attention-projection matrices ----------------
__global__ __launch_bounds__(256) void fill_weff(const float* __restrict__ Wsrc,
                                                 const float* __restrict__ Wdst,
                                                 const float* __restrict__ asrc,
                                                 const float* __restrict__ adst,
                                                 float* __restrict__ weff)
{
    int idx = blockIdx.x * 256 + threadIdx.x;
    if (idx >= 81920) return;
    int col = idx & 31;
    int k   = (idx >> 5) & 255;
    int lnt = idx >> 13;
    int nt  = lnt % 5;
    int l   = lnt / 5;
    bool is_src; int t, h;
    if (nt == 0) {
        if (col < 16) { is_src = true;  t = (col >> 2) * 2;            h = col & 3; }
        else          { is_src = false; t = ((col - 16) >> 2) * 2 + 1; h = col & 3; }
    } else {
        if (col < 4)      { is_src = true;  t = 2 * nt - 1; h = col; }
        else if (col < 8) { is_src = false; t = 2 * nt - 2; h = col - 4; }
        else { weff[idx] = 0.f; return; }
    }
    const float* W = (is_src ? Wsrc : Wdst) + ((size_t)((l * 8 + t) * 256 + k)) * 256 + h * 64;
    const float* a = (is_src ? asrc : adst) + ((size_t)((l * 8 + t) * 4 + h)) * 64;
    float val = 0.f;
    for (int c = 0; c < 64; c++) val += W[c] * a[c];
    weff[idx] = val;
}

// ---------------- attn projections (packed-x input) ----------------
template<int NO>
__device__ __forceinline__ void attnproj_body(const unsigned* __restrict__ xrow,
                                              const float* __restrict__ W,
                                              float* __restrict__ out)
{
    float acc[NO];
#pragma unroll
    for (int j = 0; j < NO; j++) acc[j] = 0.f;
    for (int k = 0; k < 256; k += 4) {
        const uint4 xv = *(const uint4*)(xrow + k);
        float x0 = unpk(xv.x), x1 = unpk(xv.y), x2 = unpk(xv.z), x3 = unpk(xv.w);
#pragma unroll
        for (int j = 0; j < NO; j++) {
            acc[j] += x0 * W[(k + 0) * 32 + j] + x1 * W[(k + 1) * 32 + j]
                    + x2 * W[(k + 2) * 32 + j] + x3 * W[(k + 3) * 32 + j];
        }
    }
#pragma unroll
    for (int j = 0; j < NO; j++) out[j] = acc[j];
}

__global__ __launch_bounds__(256) void attnproj(const unsigned* __restrict__ x,
                                                const float* __restrict__ weff_l,
                                                float* __restrict__ attnT,
                                                float* __restrict__ attnC)
{
    int n = blockIdx.x * 256 + threadIdx.x;
    if (n >= NTOT) return;
    if (n < 50000) {
        attnproj_body<32>(x + (size_t)n * 256, weff_l, attnT + (size_t)n * 32);
    } else {
        int nt = (n < 51000) ? 1 : (n < 71000) ? 2 : (n < 76000) ? 3 : 4;
        attnproj_body<8>(x + (size_t)n * 256, weff_l + nt * 8192, attnC + (size_t)(n - 50000) * 8);
    }
}

// ---------------- CSR build ----------------
__global__ __launch_bounds__(256) void count_k(EI8 ei, int* __restrict__ cnt)
{
    int g = blockIdx.x * 256 + threadIdx.x;
    if (g >= 8 * E_N) return;
    int t = g / E_N;
    int i = g - t * E_N;
    int d = ei.p[t][E_N + i];
    atomicAdd(&cnt[c_tbase[t] + d], 1);
}

__global__ __launch_bounds__(256) void scanA(const int* __restrict__ cnt,
                                             int* __restrict__ rowptr,
                                             int* __restrict__ bsum)
{
    __shared__ int sd[256];
    int b = blockIdx.x, t = threadIdx.x;
    int base = b * 1024 + t * 4;
    int v0 = 0, v1 = 0, v2 = 0, v3 = 0;
    if (base + 0 < NDST) v0 = cnt[base + 0];
    if (base + 1 < NDST) v1 = cnt[base + 1];
    if (base + 2 < NDST) v2 = cnt[base + 2];
    if (base + 3 < NDST) v3 = cnt[base + 3];
    int s = v0 + v1 + v2 + v3;
    sd[t] = s;
    __syncthreads();
    for (int off = 1; off < 256; off <<= 1) {
        int x = 0;
        if (t >= off) x = sd[t - off];
        __syncthreads();
        if (t >= off) sd[t] += x;
        __syncthreads();
    }
    int run = sd[t] - s;
    if (t == 255) bsum[b] = sd[255];
    if (base + 0 < NDST) rowptr[base + 0] = run;          run += v0;
    if (base + 1 < NDST) rowptr[base + 1] = run;          run += v1;
    if (base + 2 < NDST) rowptr[base + 2] = run;          run += v2;
    if (base + 3 < NDST) rowptr[base + 3] = run;
}

__global__ __launch_bounds__(256) void scanB(int* __restrict__ bsum, int nb)
{
    __shared__ int sd[256];
    int t = threadIdx.x;
    int v = (t < nb) ? bsum[t] : 0;
    sd[t] = v;
    __syncthreads();
    for (int off = 1; off < 256; off <<= 1) {
        int x = 0;
        if (t >= off) x = sd[t - off];
        __syncthreads();
        if (t >= off) sd[t] += x;
        __syncthreads();
    }
    if (t < nb) bsum[t] = sd[t] - v;
}

__global__ __launch_bounds__(256) void scanC(int* __restrict__ rowptr,
                                             const int* __restrict__ bsum,
                                             int* __restrict__ cursor)
{
    int b = blockIdx.x, t = threadIdx.x;
    int off = bsum[b];
    int base = b * 1024 + t * 4;
#pragma unroll
    for (int j = 0; j < 4; j++) {
        int i = base + j;
        if (i < NDST) {
            int r = rowptr[i] + off;
            rowptr[i] = r;
            cursor[i] = r;
        }
    }
    if (b == 0 && t == 0) rowptr[NDST] = 8 * E_N;
}

__global__ __launch_bounds__(256) void place_k(EI8 ei, int* __restrict__ cursor,
                                               int* __restrict__ ssrc)
{
    int g = blockIdx.x * 256 + threadIdx.x;
    if (g >= 8 * E_N) return;
    int t = g / E_N;
    int i = g - t * E_N;
    int d = ei.p[t][E_N + i];
    int s = ei.p[t][i];
    int pos = atomicAdd(&cursor[c_tbase[t] + d], 1);
    ssrc[pos] = s;
}

// ---------------- aggregate-first ts->compact: bf16 gather, unroll-4 -----------------
__global__ __launch_bounds__(256) void aggx_k(const float* __restrict__ attnT,
                                              const float* __restrict__ attnC,
                                              const unsigned short* __restrict__ xtsbf,
                                              const int* __restrict__ rowptr,
                                              const int* __restrict__ ssrc,
                                              unsigned* __restrict__ aggx)
{
    int w = blockIdx.x * 4 + (threadIdx.x >> 6);   // 0..33999 (grid 8500)
    int lane = threadIdx.x & 63;
    int h = lane >> 4;
    int ch = (h << 6) | ((lane & 15) << 2);
    int q, dloc;
    if (w < 1000)       { q = 0; dloc = w; }
    else if (w < 21000) { q = 1; dloc = w - 1000; }
    else if (w < 26000) { q = 2; dloc = w - 21000; }
    else                { q = 3; dloc = w - 26000; }
    const int csr4[4]  = {0, 51000, 121000, 176000};
    const int soff4[4] = {0, 4, 8, 12};
    int soff = soff4[q];
    int r0 = rowptr[csr4[q] + dloc], r1 = rowptr[csr4[q] + dloc + 1];
    float ed = attnC[(size_t)w * 8 + 4 + h];
    float den = 0.f, sx = 0.f, sy = 0.f, sz = 0.f, sw = 0.f;
    int e = r0;
    for (; e + 4 <= r1; e += 4) {
        int sA = ssrc[e], sB = ssrc[e + 1], sC = ssrc[e + 2], sD = ssrc[e + 3];
        float eA = attnT[(size_t)sA * 32 + soff + h];
        float eB = attnT[(size_t)sB * 32 + soff + h];
        float eC = attnT[(size_t)sC * 32 + soff + h];
        float eD = attnT[(size_t)sD * 32 + soff + h];
        ushort4 rA = *(const ushort4*)(xtsbf + (size_t)sA * 256 + ch);
        ushort4 rB = *(const ushort4*)(xtsbf + (size_t)sB * 256 + ch);
        ushort4 rC = *(const ushort4*)(xtsbf + (size_t)sC * 256 + ch);
        ushort4 rD = *(const ushort4*)(xtsbf + (size_t)sD * 256 + ch);
        float xA = __expf(lrelu(eA + ed));
        float xB = __expf(lrelu(eB + ed));
        float xC = __expf(lrelu(eC + ed));
        float xD = __expf(lrelu(eD + ed));
        den += (xA + xB) + (xC + xD);
        sx += xA * bf2f(rA.x) + xB * bf2f(rB.x) + xC * bf2f(rC.x) + xD * bf2f(rD.x);
        sy += xA * bf2f(rA.y) + xB * bf2f(rB.y) + xC * bf2f(rC.y) + xD * bf2f(rD.y);
        sz += xA * bf2f(rA.z) + xB * bf2f(rB.z) + xC * bf2f(rC.z) + xD * bf2f(rD.z);
        sw += xA * bf2f(rA.w) + xB * bf2f(rB.w) + xC * bf2f(rC.w) + xD * bf2f(rD.w);
    }
    for (; e < r1; e++) {
        int s = ssrc[e];
        float es = attnT[(size_t)s * 32 + soff + h];
        float ex = __expf(lrelu(es + ed));
        den += ex;
        ushort4 rv = *(const ushort4*)(xtsbf + (size_t)s * 256 + ch);
        sx += ex * bf2f(rv.x); sy += ex * bf2f(rv.y);
        sz += ex * bf2f(rv.z); sw += ex * bf2f(rv.w);
    }
    float inv = 1.f / (den + 1e-16f);
    uint4 o;
    o.x = packf(sx * inv); o.y = packf(sy * inv);
    o.z = packf(sz * inv); o.w = packf(sw * inv);
    *(uint4*)(aggx + (size_t)w * 256 + ch) = o;
}

// ---------------- fused compact->ts aggregation core ----------------
__device__ __forceinline__ float4 agg_ts_core(const float* __restrict__ attnT,
                                              const float* __restrict__ attnC,
                                              const unsigned short* __restrict__ hscbf,
                                              const int* __restrict__ rowptr,
                                              const int* __restrict__ ssrc,
                                              const float* __restrict__ bconv_l,
                                              int d, int h, int ch)
{
    const int co4[4]   = {0, 1000, 21000, 26000};
    const int tb4[4]   = {1000, 71000, 126000, 184000};
    const int doff4[4] = {16, 20, 24, 28};
    const int bo4[4]   = {256, 768, 1280, 1792};
    int r0q[4], nq[4]; float edq[4];
    int mx = 0;
#pragma unroll
    for (int q = 0; q < 4; q++) {
        int a = rowptr[tb4[q] + d], b = rowptr[tb4[q] + d + 1];
        r0q[q] = a; nq[q] = b - a;
        mx = max(mx, b - a);
        edq[q] = attnT[(size_t)d * 32 + doff4[q] + h];
    }
    float den[4] = {0.f, 0.f, 0.f, 0.f};
    float sx[4] = {0.f, 0.f, 0.f, 0.f}, sy[4] = {0.f, 0.f, 0.f, 0.f};
    float sz[4] = {0.f, 0.f, 0.f, 0.f}, sw[4] = {0.f, 0.f, 0.f, 0.f};
    for (int i = 0; i < mx; i++) {
#pragma unroll
        for (int q = 0; q < 4; q++) {
            if (i < nq[q]) {
                int s = ssrc[r0q[q] + i];
                float es = attnC[(size_t)(co4[q] + s) * 8 + h];
                float ex = __expf(lrelu(es + edq[q]));
                den[q] += ex;
                ushort4 hv = *(const ushort4*)(hscbf + (size_t)(co4[q] + s) * 256 + ch);
                sx[q] += ex * bf2f(hv.x); sy[q] += ex * bf2f(hv.y);
                sz[q] += ex * bf2f(hv.z); sw[q] += ex * bf2f(hv.w);
            }
        }
    }
    float ax = 0.f, ay = 0.f, az = 0.f, aw = 0.f;
#pragma unroll
    for (int q = 0; q < 4; q++) {
        const float* b = bconv_l + bo4[q] + ch;
        float inv = 1.f / (den[q] + 1e-16f);
        ax += b[0] + sx[q] * inv; ay += b[1] + sy[q] * inv;
        az += b[2] + sz[q] * inv; aw += b[3] + sw[q] * inv;
    }
    float4 o;
    o.x = fmaxf(ax, 0.f); o.y = fmaxf(ay, 0.f);
    o.z = fmaxf(az, 0.f); o.w = fmaxf(aw, 0.f);
    return o;
}

// L1: write packed rows
__global__ __launch_bounds__(256) void agg_ts(const float* __restrict__ attnT,
                                              const float* __restrict__ attnC,
                                              const unsigned short* __restrict__ hscbf,
                                              const int* __restrict__ rowptr,
                                              const int* __restrict__ ssrc,
                                              const float* __restrict__ bconv_l,
                                              unsigned* __restrict__ xout)
{
    int d = blockIdx.x * 4 + (threadIdx.x >> 6);   // grid 12500
    int lane = threadIdx.x & 63;
    int h = lane >> 4;
    int ch = (h << 6) | ((lane & 15) << 2);
    float4 o = agg_ts_core(attnT, attnC, hscbf, rowptr, ssrc, bconv_l, d, h, ch);
    uint4 po;
    po.x = packf(o.x); po.y = packf(o.y); po.z = packf(o.z); po.w = packf(o.w);
    *(uint4*)(xout + (size_t)d * 256 + ch) = po;
}

// L2: block-reduce 4 node rows -> one 256-float partial per block (no x write)
__global__ __launch_bounds__(256) void agg_ts_pool(const float* __restrict__ attnT,
                                                   const float* __restrict__ attnC,
                                                   const unsigned short* __restrict__ hscbf,
                                                   const int* __restrict__ rowptr,
                                                   const int* __restrict__ ssrc,
                                                   const float* __restrict__ bconv_l,
                                                   float* __restrict__ part)
{
    int d = blockIdx.x * 4 + (threadIdx.x >> 6);   // grid 12500
    int lane = threadIdx.x & 63;
    int h = lane >> 4;
    int ch = (h << 6) | ((lane & 15) << 2);
    float4 o = agg_ts_core(attnT, attnC, hscbf, rowptr, ssrc, bconv_l, d, h, ch);
    __shared__ float4 red4[256];
    red4[threadIdx.x] = o;
    __syncthreads();
    if (threadIdx.x < 64) {
        float4 a = red4[threadIdx.x], b = red4[threadIdx.x + 64];
        float4 c = red4[threadIdx.x + 128], dd = red4[threadIdx.x + 192];
        float4 s;
        s.x = (a.x + b.x) + (c.x + dd.x);
        s.y = (a.y + b.y) + (c.y + dd.y);
        s.z = (a.z + b.z) + (c.z + dd.z);
        s.w = (a.w + b.w) + (c.w + dd.w);
        int cch = ((threadIdx.x >> 4) << 6) | ((threadIdx.x & 15) << 2);
        *(float4*)(part + (size_t)blockIdx.x * 256 + cch) = s;
    }
}

// reduce partials: gsum[c] = sum over 12500 block rows
__global__ __launch_bounds__(256) void colsum_part(const float* __restrict__ part,
                                                   float* __restrict__ gsum)
{
    int c = threadIdx.x;
    float s = 0.f;
    for (int r = blockIdx.x; r < 12500; r += gridDim.x) s += part[(size_t)r * 256 + c];
    atomAddF(gsum + c, s);
}

// ---------------- head ----------------
__global__ __launch_bounds__(128) void head_k(const float* __restrict__ gsum,
                                              const float* __restrict__ Wc1,
                                              const float* __restrict__ bc1,
                                              const float* __restrict__ Wc2,
                                              const float* __restrict__ bc2,
                                              float* __restrict__ out)
{
    __shared__ float g[256];
    __shared__ float red[128];
    int t = threadIdx.x;
    g[t] = gsum[t] * (1.f / 50000.f);
    g[t + 128] = gsum[t + 128] * (1.f / 50000.f);
    __syncthreads();
    float acc = bc1[t];
    for (int k = 0; k < 256; k++) acc += g[k] * Wc1[k * 128 + t];
    red[t] = fmaxf(acc, 0.f) * Wc2[t];
    __syncthreads();
    for (int sft = 64; sft > 0; sft >>= 1) {
        if (t < sft) red[t] += red[t + sft];
        __syncthreads();
    }
    if (t == 0) out[0] = red[0] + bc2[0];
}

extern "C" void kernel_launch(void* const* d_in, const int* in_sizes, int n_in,
                              void* d_out, int out_size, void* d_ws, size_t ws_size,
                              hipStream_t stream)
{
    const float* ts_x   = (const float*)d_in[0];
    const float* emb[4] = {(const float*)d_in[1], (const float*)d_in[2],
                           (const float*)d_in[3], (const float*)d_in[4]};
    const float* Wp_ts  = (const float*)d_in[5];
    const float* bp_ts  = (const float*)d_in[6];
    const float* Wp_c   = (const float*)d_in[7];
    const float* bp_c   = (const float*)d_in[8];
    const float* Wsrc   = (const float*)d_in[9];
    const float* Wdst   = (const float*)d_in[10];
    const float* asrc   = (const float*)d_in[11];
    const float* adst   = (const float*)d_in[12];
    const float* bconv  = (const float*)d_in[13];
    const float* Wc1    = (const float*)d_in[14];
    const float* bc1    = (const float*)d_in[15];
    const float* Wc2    = (const float*)d_in[16];
    const float* bc2    = (const float*)d_in[17];
    EI8 ei;
    for (int t = 0; t < 8; t++) ei.p[t] = (const int*)d_in[18 + t];

    // workspace layout (4-byte units)
    unsigned* x0p  = (unsigned*)d_ws;       // 21,504,000
    unsigned* x1p  = x0p  + 21504000;       // 21,504,000 (ts region doubles as aggx in L1)
    float* attnT = (float*)(x1p + 21504000);// 1,600,000
    float* attnC = attnT + 1600000;         // 272,000
    float* weff  = attnC + 272000;          // 81,920
    float* gsum  = weff  + 81920;           // 256
    int* rowptr  = (int*)(gsum + 256);      // 234,004
    int* bsum    = rowptr + 234004;         // 256
    int* ssrc    = bsum + 256;              // 800,000
    unsigned short* xtsbf = (unsigned short*)(ssrc + 800000);   // 12,800,000 us
    unsigned short* hscbf = xtsbf + 12800000;                   //  8,704,000 us
    unsigned short* btp   = hscbf + 8704000;                    //  1,867,776 us
    int* cursor  = (int*)hscbf;             // alias: CSR build finishes before hscbf used
    unsigned* aggx = x1p;                   // alias ts region of x1p
    float* part  = (float*)x0p;             // alias: x0p dead by the time L2 agg runs

    unsigned short* bt_ts_h = btp;
    unsigned short* bt_ts_l = bt_ts_h + 16384;
    unsigned short* bt_c_h[4], *bt_c_l[4];
    {
        unsigned short* p = bt_ts_l + 16384;
        for (int q = 0; q < 4; q++) { bt_c_h[q] = p; p += 32768; bt_c_l[q] = p; p += 32768; }
    }
    unsigned short* bt_w = bt_ts_l + 16384 + 8 * 32768;
    auto wpan_h = [&](int l, int t) { return bt_w + (size_t)((l == 0 ? t : 8 + t / 2) * 2) * 65536; };
    auto wpan_l = [&](int l, int t) { return wpan_h(l, t) + 65536; };

    // ---- CSR build ----
    hipMemsetAsync(cursor, 0, NDST * sizeof(int), stream);
    count_k<<<3125, 256, 0, stream>>>(ei, cursor);
    scanA<<<229, 256, 0, stream>>>(cursor, rowptr, bsum);
    scanB<<<1, 256, 0, stream>>>(bsum, 229);
    scanC<<<229, 256, 0, stream>>>(rowptr, bsum, cursor);
    place_k<<<3125, 256, 0, stream>>>(ei, cursor, ssrc);

    // ---- weight pre-split ----
    {
        BTBatch b = {};
        int zi = 0;
        b.j[zi++] = {Wp_ts, bt_ts_h, bt_ts_l, 64, 6};
        for (int q = 0; q < 4; q++)
            b.j[zi++] = {Wp_c + q * 32768, bt_c_h[q], bt_c_l[q], 128, 7};
        for (int t = 0; t < 8; t++)
            b.j[zi++] = {Wsrc + (size_t)(0 * 8 + t) * 65536, wpan_h(0, t), wpan_l(0, t), 256, 8};
        for (int t = 1; t < 8; t += 2)
            b.j[zi++] = {Wsrc + (size_t)(1 * 8 + t) * 65536, wpan_h(1, t), wpan_l(1, t), 256, 8};
        makeBT<<<dim3(256, 1, 17), 256, 0, stream>>>(b);
    }

    fill_weff<<<320, 256, 0, stream>>>(Wsrc, Wdst, asrc, adst, weff);

    static const int Nd4[4]    = {1000, 20000, 5000, 8000};
    static const int co4[4]    = {0, 1000, 21000, 26000};
    static const int dbase4[4] = {50000, 51000, 71000, 76000};
    static const int tsrc[4]   = {1, 3, 5, 7};
    static const int tdst[4]   = {0, 2, 4, 6};

    // ---- input projections (fp32 A path); ts job also writes bf16 hi shadow ----
    {
        MBatch b = {};
        b.j[0] = {ts_x, bt_ts_h, bt_ts_l, x0p, xtsbf, bp_ts, 50000, 64, 0, 1};
        for (int q = 0; q < 4; q++)
            b.j[1 + q] = {emb[q], bt_c_h[q], bt_c_l[q], x0p + (size_t)dbase4[q] * 256,
                          nullptr, bp_c + q * 256, Nd4[q], 128, 0, 1};
        gemm_mfma<<<dim3(391, 2, 5), 256, 0, stream>>>(b);
    }

    // ---- layer 1 ----
    attnproj<<<329, 256, 0, stream>>>(x0p, weff, attnT, attnC);
    aggx_k<<<8500, 256, 0, stream>>>(attnT, attnC, xtsbf, rowptr, ssrc, aggx);
    {
        MBatch b = {};
        for (int q = 0; q < 4; q++)
            b.j[q] = {x0p + (size_t)dbase4[q] * 256, wpan_h(0, tsrc[q]), wpan_l(0, tsrc[q]),
                      nullptr, hscbf + (size_t)co4[q] * 256, nullptr, Nd4[q], 256, 0, 0};
        for (int q = 0; q < 4; q++)
            b.j[4 + q] = {aggx + (size_t)co4[q] * 256, wpan_h(0, tdst[q]), wpan_l(0, tdst[q]),
                          x1p + (size_t)dbase4[q] * 256, nullptr, bconv + tdst[q] * 256, Nd4[q], 256, 1, 0};
        gemm_mfma<<<dim3(157, 2, 8), 256, 0, stream>>>(b);
    }
    agg_ts<<<12500, 256, 0, stream>>>(attnT, attnC, hscbf, rowptr, ssrc, bconv, x1p);

    // ---- layer 2 (ts outputs only, pooled via per-block partials) ----
    attnproj<<<329, 256, 0, stream>>>(x1p, weff + 40960, attnT, attnC);
    {
        MBatch b = {};
        for (int q = 0; q < 4; q++)
            b.j[q] = {x1p + (size_t)dbase4[q] * 256, wpan_h(1, tsrc[q]), wpan_l(1, tsrc[q]),
                      nullptr, hscbf + (size_t)co4[q] * 256, nullptr, Nd4[q], 256, 0, 0};
        gemm_mfma<<<dim3(157, 2, 4), 256, 0, stream>>>(b);
    }
    agg_ts_pool<<<12500, 256, 0, stream>>>(attnT, attnC, hscbf, rowptr, ssrc, bconv + 2048, part);
    hipMemsetAsync(gsum, 0, 256 * sizeof(float), stream);
    colsum_part<<<256, 256, 0, stream>>>(part, gsum);

    head_k<<<1, 128, 0, stream>>>(gsum, Wc1, bc1, Wc2, bc2, (float*)d_out);
}

// Round 8
// 723.512 us; speedup vs baseline: 1.3237x; 1.1516x over previous
//
#include <hip/hip_runtime.h>

#define E_N 100000
#define NTOT 84000
#define NDST 234000   // concatenated per-type dst index space

typedef __attribute__((ext_vector_type(8))) short bfrag8;
typedef __attribute__((ext_vector_type(4))) float accf4;

__device__ __forceinline__ void atomAddF(float* p, float v) {
    unsafeAtomicAdd(p, v);
}

__device__ __forceinline__ float lrelu(float v) { return v >= 0.f ? v : 0.2f * v; }

// fp32 -> bf16 round-to-nearest-even, and back
__device__ __forceinline__ unsigned short f2bf(float f) {
    unsigned u = __float_as_uint(f);
    return (unsigned short)((u + 0x7FFFu + ((u >> 16) & 1u)) >> 16);
}
__device__ __forceinline__ float bf2f(unsigned short h) {
    return __uint_as_float(((unsigned)h) << 16);
}

// CSR dst-space bases per edge type t
__constant__ int c_tbase[8] = {0, 1000, 51000, 71000, 121000, 126000, 176000, 184000};

struct EI8 { const int* p[8]; };

// ---------------- weight pre-split: W[K][256] fp32 -> BThi/BTlo[256][K] bf16 ----------
struct BTJob { const float* W; unsigned short* hi; unsigned short* lo; int K; int kshift; };
struct BTBatch { BTJob j[17]; };

__global__ __launch_bounds__(256) void makeBT(BTBatch b)
{
    BTJob jb = b.j[blockIdx.z];
    int idx = blockIdx.x * 256 + threadIdx.x;   // n*K + k
    if (idx >= (jb.K << 8)) return;
    int n = idx >> jb.kshift;
    int k = idx & (jb.K - 1);
    float w = jb.W[(size_t)k * 256 + n];
    unsigned short h = f2bf(w);
    jb.hi[idx] = h;
    jb.lo[idx] = f2bf(w - bf2f(h));
}

// ---------------- MFMA split-bf16 GEMM: C[M x 256] = A[M x K] @ B[K x 256] ------------
// 128x128 tile, 4 waves in 2x2 quadrants, 4x4 MFMA 16x16x32 tiles each.
// acc += Ahi*B1 + Alo*B1 + Ahi*B2 (missing Alo*B2 ~2^-16 relative).
// Block decode: the two column-half blocks of a row-tile are 8 ids apart -> same XCD
// under round-robin dispatch -> second A read served from that XCD's L2.
struct MJob { const float* A; const unsigned short* BThi; const unsigned short* BTlo;
              float* C; unsigned short* Cbf; const float* bias; int M; int K; int relu; };
struct MBatch { MJob j[8]; };

__global__ __launch_bounds__(256, 2) void gemm_mfma(MBatch batch)
{
    const MJob jb = batch.j[blockIdx.z];
    // decode: group of 16 ids = 8 row-tiles x 2 col-halves, halves 8 apart
    const int bx = blockIdx.x;
    const int rowblk = (bx >> 4) * 8 + (bx & 7);
    const int half = (bx >> 3) & 1;
    const int bm = rowblk * 128;
    if (bm >= jb.M) return;
    const int bn = half * 128;
    const int M = jb.M, K = jb.K;

    __shared__ unsigned short Ah[128 * 40];
    __shared__ unsigned short Al[128 * 40];
    __shared__ unsigned short B1[128 * 40];
    __shared__ unsigned short B2[128 * 40];

    const int tid  = threadIdx.x;
    const int wv   = tid >> 6;
    const int lane = tid & 63;
    const int qr = wv >> 1, qc = wv & 1;
    const int lm = lane & 15;
    const int lq = lane >> 4;

    accf4 acc[4][4] = {};   // [mt][nt]

    for (int k0 = 0; k0 < K; k0 += 32) {
        // ---- stage A: 128 rows x 32 fp32, split hi/lo ----
#pragma unroll
        for (int it = 0; it < 4; ++it) {
            int slot = it * 256 + tid;       // 0..1023
            int m  = slot >> 3;              // 0..127
            int kq = (slot & 7) << 2;        // 0,4,...,28
            float4 v = make_float4(0.f, 0.f, 0.f, 0.f);
            if (bm + m < M) v = *(const float4*)(jb.A + (size_t)(bm + m) * K + k0 + kq);
            int o = m * 40 + kq;
            unsigned short h0 = f2bf(v.x), h1 = f2bf(v.y), h2 = f2bf(v.z), h3 = f2bf(v.w);
            Ah[o + 0] = h0; Ah[o + 1] = h1; Ah[o + 2] = h2; Ah[o + 3] = h3;
            Al[o + 0] = f2bf(v.x - bf2f(h0));
            Al[o + 1] = f2bf(v.y - bf2f(h1));
            Al[o + 2] = f2bf(v.z - bf2f(h2));
            Al[o + 3] = f2bf(v.w - bf2f(h3));
        }
        // ---- stage B: two panels, 128 n-rows x 32 k (bf16, transposed) ----
#pragma unroll
        for (int it = 0; it < 2; ++it) {
            int slot = it * 256 + tid;       // 0..511
            int n  = slot >> 2;              // 0..127
            int kq = (slot & 3) << 3;        // 0,8,16,24
            size_t go = (size_t)(bn + n) * K + k0 + kq;
            *(uint4*)&B1[n * 40 + kq] = *(const uint4*)(jb.BThi + go);
            *(uint4*)&B2[n * 40 + kq] = *(const uint4*)(jb.BTlo + go);
        }
        __syncthreads();

        bfrag8 ah[4], al[4], b1[4], b2[4];
#pragma unroll
        for (int t = 0; t < 4; ++t) {
            int am  = qr * 64 + t * 16 + lm;
            int bnn = qc * 64 + t * 16 + lm;
            ah[t] = *(const bfrag8*)&Ah[am * 40 + lq * 8];
            al[t] = *(const bfrag8*)&Al[am * 40 + lq * 8];
            b1[t] = *(const bfrag8*)&B1[bnn * 40 + lq * 8];
            b2[t] = *(const bfrag8*)&B2[bnn * 40 + lq * 8];
        }
#pragma unroll
        for (int mt = 0; mt < 4; ++mt)
#pragma unroll
            for (int nt = 0; nt < 4; ++nt) {
                acc[mt][nt] = __builtin_amdgcn_mfma_f32_16x16x32_bf16(ah[mt], b1[nt], acc[mt][nt], 0, 0, 0);
                acc[mt][nt] = __builtin_amdgcn_mfma_f32_16x16x32_bf16(al[mt], b1[nt], acc[mt][nt], 0, 0, 0);
                acc[mt][nt] = __builtin_amdgcn_mfma_f32_16x16x32_bf16(ah[mt], b2[nt], acc[mt][nt], 0, 0, 0);
            }
        __syncthreads();
    }

    // ---- epilogue: C/D layout col=lane&15, row=(lane>>4)*4+r ----
#pragma unroll
    for (int nt = 0; nt < 4; ++nt) {
        int col = bn + qc * 64 + nt * 16 + lm;
        float bv = jb.bias ? jb.bias[col] : 0.f;
#pragma unroll
        for (int mt = 0; mt < 4; ++mt) {
            int row0 = bm + qr * 64 + mt * 16 + lq * 4;
#pragma unroll
            for (int r = 0; r < 4; ++r) {
                int row = row0 + r;
                if (row < M) {
                    float o = acc[mt][nt][r] + bv;
                    if (jb.relu) o = fmaxf(o, 0.f);
                    if (jb.C)   jb.C[(size_t)row * 256 + col] = o;
                    if (jb.Cbf) jb.Cbf[(size_t)row * 256 + col] = f2bf(o);
                }
            }
        }
    }
}

// ---------------- effective attention-projection matrices ----------------
__global__ __launch_bounds__(256) void fill_weff(const float* __restrict__ Wsrc,
                                                 const float* __restrict__ Wdst,
                                                 const float* __restrict__ asrc,
                                                 const float* __restrict__ adst,
                                                 float* __restrict__ weff)
{
    int idx = blockIdx.x * 256 + threadIdx.x;
    if (idx >= 81920) return;
    int col = idx & 31;
    int k   = (idx >> 5) & 255;
    int lnt = idx >> 13;
    int nt  = lnt % 5;
    int l   = lnt / 5;
    bool is_src; int t, h;
    if (nt == 0) {
        if (col < 16) { is_src = true;  t = (col >> 2) * 2;            h = col & 3; }
        else          { is_src = false; t = ((col - 16) >> 2) * 2 + 1; h = col & 3; }
    } else {
        if (col < 4)      { is_src = true;  t = 2 * nt - 1; h = col; }
        else if (col < 8) { is_src = false; t = 2 * nt - 2; h = col - 4; }
        else { weff[idx] = 0.f; return; }
    }
    const float* W = (is_src ? Wsrc : Wdst) + ((size_t)((l * 8 + t) * 256 + k)) * 256 + h * 64;
    const float* a = (is_src ? asrc : adst) + ((size_t)((l * 8 + t) * 4 + h)) * 64;
    float val = 0.f;
    for (int c = 0; c < 64; c++) val += W[c] * a[c];
    weff[idx] = val;
}

// ---------------- attn projections ----------------
template<int NO>
__device__ __forceinline__ void attnproj_body(const float* __restrict__ xrow,
                                              const float* __restrict__ W,
                                              float* __restrict__ out)
{
    float acc[NO];
#pragma unroll
    for (int j = 0; j < NO; j++) acc[j] = 0.f;
    for (int k = 0; k < 256; k += 4) {
        const float4 xv = *(const float4*)(xrow + k);
#pragma unroll
        for (int j = 0; j < NO; j++) {
            acc[j] += xv.x * W[(k + 0) * 32 + j] + xv.y * W[(k + 1) * 32 + j]
                    + xv.z * W[(k + 2) * 32 + j] + xv.w * W[(k + 3) * 32 + j];
        }
    }
#pragma unroll
    for (int j = 0; j < NO; j++) out[j] = acc[j];
}

__global__ __launch_bounds__(256) void attnproj(const float* __restrict__ x,
                                                const float* __restrict__ weff_l,
                                                float* __restrict__ attnT,
                                                float* __restrict__ attnC)
{
    int n = blockIdx.x * 256 + threadIdx.x;
    if (n >= NTOT) return;
    if (n < 50000) {
        attnproj_body<32>(x + (size_t)n * 256, weff_l, attnT + (size_t)n * 32);
    } else {
        int nt = (n < 51000) ? 1 : (n < 71000) ? 2 : (n < 76000) ? 3 : 4;
        attnproj_body<8>(x + (size_t)n * 256, weff_l + nt * 8192, attnC + (size_t)(n - 50000) * 8);
    }
}

// ---------------- CSR build ----------------
__global__ __launch_bounds__(256) void count_k(EI8 ei, int* __restrict__ cnt)
{
    int g = blockIdx.x * 256 + threadIdx.x;
    if (g >= 8 * E_N) return;
    int t = g / E_N;
    int i = g - t * E_N;
    int d = ei.p[t][E_N + i];
    atomicAdd(&cnt[c_tbase[t] + d], 1);
}

__global__ __launch_bounds__(256) void scanA(const int* __restrict__ cnt,
                                             int* __restrict__ rowptr,
                                             int* __restrict__ bsum)
{
    __shared__ int sd[256];
    int b = blockIdx.x, t = threadIdx.x;
    int base = b * 1024 + t * 4;
    int v0 = 0, v1 = 0, v2 = 0, v3 = 0;
    if (base + 0 < NDST) v0 = cnt[base + 0];
    if (base + 1 < NDST) v1 = cnt[base + 1];
    if (base + 2 < NDST) v2 = cnt[base + 2];
    if (base + 3 < NDST) v3 = cnt[base + 3];
    int s = v0 + v1 + v2 + v3;
    sd[t] = s;
    __syncthreads();
    for (int off = 1; off < 256; off <<= 1) {
        int x = 0;
        if (t >= off) x = sd[t - off];
        __syncthreads();
        if (t >= off) sd[t] += x;
        __syncthreads();
    }
    int run = sd[t] - s;
    if (t == 255) bsum[b] = sd[255];
    if (base + 0 < NDST) rowptr[base + 0] = run;          run += v0;
    if (base + 1 < NDST) rowptr[base + 1] = run;          run += v1;
    if (base + 2 < NDST) rowptr[base + 2] = run;          run += v2;
    if (base + 3 < NDST) rowptr[base + 3] = run;
}

__global__ __launch_bounds__(256) void scanB(int* __restrict__ bsum, int nb)
{
    __shared__ int sd[256];
    int t = threadIdx.x;
    int v = (t < nb) ? bsum[t] : 0;
    sd[t] = v;
    __syncthreads();
    for (int off = 1; off < 256; off <<= 1) {
        int x = 0;
        if (t >= off) x = sd[t - off];
        __syncthreads();
        if (t >= off) sd[t] += x;
        __syncthreads();
    }
    if (t < nb) bsum[t] = sd[t] - v;
}

__global__ __launch_bounds__(256) void scanC(int* __restrict__ rowptr,
                                             const int* __restrict__ bsum,
                                             int* __restrict__ cursor)
{
    int b = blockIdx.x, t = threadIdx.x;
    int off = bsum[b];
    int base = b * 1024 + t * 4;
#pragma unroll
    for (int j = 0; j < 4; j++) {
        int i = base + j;
        if (i < NDST) {
            int r = rowptr[i] + off;
            rowptr[i] = r;
            cursor[i] = r;
        }
    }
    if (b == 0 && t == 0) rowptr[NDST] = 8 * E_N;
}

__global__ __launch_bounds__(256) void place_k(EI8 ei, int* __restrict__ cursor,
                                               int* __restrict__ ssrc)
{
    int g = blockIdx.x * 256 + threadIdx.x;
    if (g >= 8 * E_N) return;
    int t = g / E_N;
    int i = g - t * E_N;
    int d = ei.p[t][E_N + i];
    int s = ei.p[t][i];
    int pos = atomicAdd(&cursor[c_tbase[t] + d], 1);
    ssrc[pos] = s;
}

// ---------------- aggregate-first ts->compact: bf16 gather, unroll-4 -----------------
__global__ __launch_bounds__(256) void aggx_k(const float* __restrict__ attnT,
                                              const float* __restrict__ attnC,
                                              const unsigned short* __restrict__ xtsbf,
                                              const int* __restrict__ rowptr,
                                              const int* __restrict__ ssrc,
                                              float* __restrict__ aggx)
{
    int w = blockIdx.x * 4 + (threadIdx.x >> 6);   // 0..33999 (grid 8500)
    int lane = threadIdx.x & 63;
    int h = lane >> 4;
    int ch = (h << 6) | ((lane & 15) << 2);
    int q, dloc;
    if (w < 1000)       { q = 0; dloc = w; }
    else if (w < 21000) { q = 1; dloc = w - 1000; }
    else if (w < 26000) { q = 2; dloc = w - 21000; }
    else                { q = 3; dloc = w - 26000; }
    const int csr4[4]  = {0, 51000, 121000, 176000};
    const int soff4[4] = {0, 4, 8, 12};
    int soff = soff4[q];
    int r0 = rowptr[csr4[q] + dloc], r1 = rowptr[csr4[q] + dloc + 1];
    float ed = attnC[(size_t)w * 8 + 4 + h];
    float den = 0.f, sx = 0.f, sy = 0.f, sz = 0.f, sw = 0.f;
    int e = r0;
    for (; e + 4 <= r1; e += 4) {
        int sA = ssrc[e], sB = ssrc[e + 1], sC = ssrc[e + 2], sD = ssrc[e + 3];
        float eA = attnT[(size_t)sA * 32 + soff + h];
        float eB = attnT[(size_t)sB * 32 + soff + h];
        float eC = attnT[(size_t)sC * 32 + soff + h];
        float eD = attnT[(size_t)sD * 32 + soff + h];
        ushort4 rA = *(const ushort4*)(xtsbf + (size_t)sA * 256 + ch);
        ushort4 rB = *(const ushort4*)(xtsbf + (size_t)sB * 256 + ch);
        ushort4 rC = *(const ushort4*)(xtsbf + (size_t)sC * 256 + ch);
        ushort4 rD = *(const ushort4*)(xtsbf + (size_t)sD * 256 + ch);
        float xA = __expf(lrelu(eA + ed));
        float xB = __expf(lrelu(eB + ed));
        float xC = __expf(lrelu(eC + ed));
        float xD = __expf(lrelu(eD + ed));
        den += (xA + xB) + (xC + xD);
        sx += xA * bf2f(rA.x) + xB * bf2f(rB.x) + xC * bf2f(rC.x) + xD * bf2f(rD.x);
        sy += xA * bf2f(rA.y) + xB * bf2f(rB.y) + xC * bf2f(rC.y) + xD * bf2f(rD.y);
        sz += xA * bf2f(rA.z) + xB * bf2f(rB.z) + xC * bf2f(rC.z) + xD * bf2f(rD.z);
        sw += xA * bf2f(rA.w) + xB * bf2f(rB.w) + xC * bf2f(rC.w) + xD * bf2f(rD.w);
    }
    for (; e < r1; e++) {
        int s = ssrc[e];
        float es = attnT[(size_t)s * 32 + soff + h];
        float ex = __expf(lrelu(es + ed));
        den += ex;
        ushort4 rv = *(const ushort4*)(xtsbf + (size_t)s * 256 + ch);
        sx += ex * bf2f(rv.x); sy += ex * bf2f(rv.y);
        sz += ex * bf2f(rv.z); sw += ex * bf2f(rv.w);
    }
    float inv = 1.f / (den + 1e-16f);
    float4 o; o.x = sx * inv; o.y = sy * inv; o.z = sz * inv; o.w = sw * inv;
    *(float4*)(aggx + (size_t)w * 256 + ch) = o;
}

// ---------------- fused compact->ts aggregation core ----------------
__device__ __forceinline__ float4 agg_ts_core(const float* __restrict__ attnT,
                                              const float* __restrict__ attnC,
                                              const unsigned short* __restrict__ hscbf,
                                              const int* __restrict__ rowptr,
                                              const int* __restrict__ ssrc,
                                              const float* __restrict__ bconv_l,
                                              int d, int h, int ch)
{
    const int co4[4]   = {0, 1000, 21000, 26000};
    const int tb4[4]   = {1000, 71000, 126000, 184000};
    const int doff4[4] = {16, 20, 24, 28};
    const int bo4[4]   = {256, 768, 1280, 1792};
    int r0q[4], nq[4]; float edq[4];
    int mx = 0;
#pragma unroll
    for (int q = 0; q < 4; q++) {
        int a = rowptr[tb4[q] + d], b = rowptr[tb4[q] + d + 1];
        r0q[q] = a; nq[q] = b - a;
        mx = max(mx, b - a);
        edq[q] = attnT[(size_t)d * 32 + doff4[q] + h];
    }
    float den[4] = {0.f, 0.f, 0.f, 0.f};
    float sx[4] = {0.f, 0.f, 0.f, 0.f}, sy[4] = {0.f, 0.f, 0.f, 0.f};
    float sz[4] = {0.f, 0.f, 0.f, 0.f}, sw[4] = {0.f, 0.f, 0.f, 0.f};
    for (int i = 0; i < mx; i++) {
#pragma unroll
        for (int q = 0; q < 4; q++) {
            if (i < nq[q]) {
                int s = ssrc[r0q[q] + i];
                float es = attnC[(size_t)(co4[q] + s) * 8 + h];
                float ex = __expf(lrelu(es + edq[q]));
                den[q] += ex;
                ushort4 hv = *(const ushort4*)(hscbf + (size_t)(co4[q] + s) * 256 + ch);
                sx[q] += ex * bf2f(hv.x); sy[q] += ex * bf2f(hv.y);
                sz[q] += ex * bf2f(hv.z); sw[q] += ex * bf2f(hv.w);
            }
        }
    }
    float ax = 0.f, ay = 0.f, az = 0.f, aw = 0.f;
#pragma unroll
    for (int q = 0; q < 4; q++) {
        const float* b = bconv_l + bo4[q] + ch;
        float inv = 1.f / (den[q] + 1e-16f);
        ax += b[0] + sx[q] * inv; ay += b[1] + sy[q] * inv;
        az += b[2] + sz[q] * inv; aw += b[3] + sw[q] * inv;
    }
    float4 o;
    o.x = fmaxf(ax, 0.f); o.y = fmaxf(ay, 0.f);
    o.z = fmaxf(az, 0.f); o.w = fmaxf(aw, 0.f);
    return o;
}

// L1: write fp32 rows
__global__ __launch_bounds__(256) void agg_ts(const float* __restrict__ attnT,
                                              const float* __restrict__ attnC,
                                              const unsigned short* __restrict__ hscbf,
                                              const int* __restrict__ rowptr,
                                              const int* __restrict__ ssrc,
                                              const float* __restrict__ bconv_l,
                                              float* __restrict__ xout)
{
    int d = blockIdx.x * 4 + (threadIdx.x >> 6);   // grid 12500
    int lane = threadIdx.x & 63;
    int h = lane >> 4;
    int ch = (h << 6) | ((lane & 15) << 2);
    float4 o = agg_ts_core(attnT, attnC, hscbf, rowptr, ssrc, bconv_l, d, h, ch);
    *(float4*)(xout + (size_t)d * 256 + ch) = o;
}

// L2: block-reduce 4 node rows -> one 256-float partial per block (no x write)
__global__ __launch_bounds__(256) void agg_ts_pool(const float* __restrict__ attnT,
                                                   const float* __restrict__ attnC,
                                                   const unsigned short* __restrict__ hscbf,
                                                   const int* __restrict__ rowptr,
                                                   const int* __restrict__ ssrc,
                                                   const float* __restrict__ bconv_l,
                                                   float* __restrict__ part)
{
    int d = blockIdx.x * 4 + (threadIdx.x >> 6);   // grid 12500
    int lane = threadIdx.x & 63;
    int h = lane >> 4;
    int ch = (h << 6) | ((lane & 15) << 2);
    float4 o = agg_ts_core(attnT, attnC, hscbf, rowptr, ssrc, bconv_l, d, h, ch);
    __shared__ float4 red4[256];
    red4[threadIdx.x] = o;
    __syncthreads();
    if (threadIdx.x < 64) {
        float4 a = red4[threadIdx.x], b = red4[threadIdx.x + 64];
        float4 c = red4[threadIdx.x + 128], dd = red4[threadIdx.x + 192];
        float4 s;
        s.x = (a.x + b.x) + (c.x + dd.x);
        s.y = (a.y + b.y) + (c.y + dd.y);
        s.z = (a.z + b.z) + (c.z + dd.z);
        s.w = (a.w + b.w) + (c.w + dd.w);
        int cch = ((threadIdx.x >> 4) << 6) | ((threadIdx.x & 15) << 2);
        *(float4*)(part + (size_t)blockIdx.x * 256 + cch) = s;
    }
}

// reduce partials: gsum[c] = sum over 12500 block rows
__global__ __launch_bounds__(256) void colsum_part(const float* __restrict__ part,
                                                   float* __restrict__ gsum)
{
    int c = threadIdx.x;
    float s = 0.f;
    for (int r = blockIdx.x; r < 12500; r += gridDim.x) s += part[(size_t)r * 256 + c];
    atomAddF(gsum + c, s);
}

// ---------------- head ----------------
__global__ __launch_bounds__(128) void head_k(const float* __restrict__ gsum,
                                              const float* __restrict__ Wc1,
                                              const float* __restrict__ bc1,
                                              const float* __restrict__ Wc2,
                                              const float* __restrict__ bc2,
                                              float* __restrict__ out)
{
    __shared__ float g[256];
    __shared__ float red[128];
    int t = threadIdx.x;
    g[t] = gsum[t] * (1.f / 50000.f);
    g[t + 128] = gsum[t + 128] * (1.f / 50000.f);
    __syncthreads();
    float acc = bc1[t];
    for (int k = 0; k < 256; k++) acc += g[k] * Wc1[k * 128 + t];
    red[t] = fmaxf(acc, 0.f) * Wc2[t];
    __syncthreads();
    for (int sft = 64; sft > 0; sft >>= 1) {
        if (t < sft) red[t] += red[t + sft];
        __syncthreads();
    }
    if (t == 0) out[0] = red[0] + bc2[0];
}

extern "C" void kernel_launch(void* const* d_in, const int* in_sizes, int n_in,
                              void* d_out, int out_size, void* d_ws, size_t ws_size,
                              hipStream_t stream)
{
    const float* ts_x   = (const float*)d_in[0];
    const float* emb[4] = {(const float*)d_in[1], (const float*)d_in[2],
                           (const float*)d_in[3], (const float*)d_in[4]};
    const float* Wp_ts  = (const float*)d_in[5];
    const float* bp_ts  = (const float*)d_in[6];
    const float* Wp_c   = (const float*)d_in[7];
    const float* bp_c   = (const float*)d_in[8];
    const float* Wsrc   = (const float*)d_in[9];
    const float* Wdst   = (const float*)d_in[10];
    const float* asrc   = (const float*)d_in[11];
    const float* adst   = (const float*)d_in[12];
    const float* bconv  = (const float*)d_in[13];
    const float* Wc1    = (const float*)d_in[14];
    const float* bc1    = (const float*)d_in[15];
    const float* Wc2    = (const float*)d_in[16];
    const float* bc2    = (const float*)d_in[17];
    EI8 ei;
    for (int t = 0; t < 8; t++) ei.p[t] = (const int*)d_in[18 + t];

    // workspace layout (float units)
    float* x0    = (float*)d_ws;           // 21,504,000
    float* x1    = x0    + 21504000;       // 21,504,000 (ts region doubles as aggx in L1)
    float* attnT = x1    + 21504000;       // 1,600,000
    float* attnC = attnT + 1600000;        // 272,000
    float* weff  = attnC + 272000;         // 81,920
    float* gsum  = weff  + 81920;          // 256
    int* rowptr  = (int*)(gsum + 256);     // 234,004
    int* bsum    = rowptr + 234004;        // 256
    int* ssrc    = bsum + 256;             // 800,000
    unsigned short* xtsbf = (unsigned short*)(ssrc + 800000);   // 12,800,000 us
    unsigned short* hscbf = xtsbf + 12800000;                   //  8,704,000 us
    unsigned short* btp   = hscbf + 8704000;                    //  1,867,776 us
    int* cursor  = (int*)hscbf;            // alias: CSR build finishes before hscbf used
    float* aggx  = x1;                     // alias ts region of x1
    float* part  = x0;                     // alias: x0 dead by the time L2 agg runs

    unsigned short* bt_ts_h = btp;
    unsigned short* bt_ts_l = bt_ts_h + 16384;
    unsigned short* bt_c_h[4], *bt_c_l[4];
    {
        unsigned short* p = bt_ts_l + 16384;
        for (int q = 0; q < 4; q++) { bt_c_h[q] = p; p += 32768; bt_c_l[q] = p; p += 32768; }
    }
    unsigned short* bt_w = bt_ts_l + 16384 + 8 * 32768;
    auto wpan_h = [&](int l, int t) { return bt_w + (size_t)((l == 0 ? t : 8 + t / 2) * 2) * 65536; };
    auto wpan_l = [&](int l, int t) { return wpan_h(l, t) + 65536; };

    // ---- CSR build ----
    hipMemsetAsync(cursor, 0, NDST * sizeof(int), stream);
    count_k<<<3125, 256, 0, stream>>>(ei, cursor);
    scanA<<<229, 256, 0, stream>>>(cursor, rowptr, bsum);
    scanB<<<1, 256, 0, stream>>>(bsum, 229);
    scanC<<<229, 256, 0, stream>>>(rowptr, bsum, cursor);
    place_k<<<3125, 256, 0, stream>>>(ei, cursor, ssrc);

    // ---- weight pre-split ----
    {
        BTBatch b = {};
        int zi = 0;
        b.j[zi++] = {Wp_ts, bt_ts_h, bt_ts_l, 64, 6};
        for (int q = 0; q < 4; q++)
            b.j[zi++] = {Wp_c + q * 32768, bt_c_h[q], bt_c_l[q], 128, 7};
        for (int t = 0; t < 8; t++)
            b.j[zi++] = {Wsrc + (size_t)(0 * 8 + t) * 65536, wpan_h(0, t), wpan_l(0, t), 256, 8};
        for (int t = 1; t < 8; t += 2)
            b.j[zi++] = {Wsrc + (size_t)(1 * 8 + t) * 65536, wpan_h(1, t), wpan_l(1, t), 256, 8};
        makeBT<<<dim3(256, 1, 17), 256, 0, stream>>>(b);
    }

    fill_weff<<<320, 256, 0, stream>>>(Wsrc, Wdst, asrc, adst, weff);

    static const int Nd4[4]    = {1000, 20000, 5000, 8000};
    static const int co4[4]    = {0, 1000, 21000, 26000};
    static const int dbase4[4] = {50000, 51000, 71000, 76000};
    static const int tsrc[4]   = {1, 3, 5, 7};
    static const int tdst[4]   = {0, 2, 4, 6};

    // grid.x for gemm: 2*ceil(M/128) padded to multiple of 16 (paired-half decode)
    // proj: max M=50000 -> 391 rowblks -> 782 -> 784 ; L1/L2: max M=20000 -> 157 -> 314 -> 320
    // ---- input projections (ts job also writes bf16 shadow for aggx gather) ----
    {
        MBatch b = {};
        b.j[0] = {ts_x, bt_ts_h, bt_ts_l, x0, xtsbf, bp_ts, 50000, 64, 0};
        for (int q = 0; q < 4; q++)
            b.j[1 + q] = {emb[q], bt_c_h[q], bt_c_l[q], x0 + (size_t)dbase4[q] * 256,
                          nullptr, bp_c + q * 256, Nd4[q], 128, 0};
        gemm_mfma<<<dim3(784, 1, 5), 256, 0, stream>>>(b);
    }

    // ---- layer 1 ----
    attnproj<<<329, 256, 0, stream>>>(x0, weff, attnT, attnC);
    aggx_k<<<8500, 256, 0, stream>>>(attnT, attnC, xtsbf, rowptr, ssrc, aggx);
    {
        MBatch b = {};
        for (int q = 0; q < 4; q++)
            b.j[q] = {x0 + (size_t)dbase4[q] * 256, wpan_h(0, tsrc[q]), wpan_l(0, tsrc[q]),
                      nullptr, hscbf + (size_t)co4[q] * 256, nullptr, Nd4[q], 256, 0};
        for (int q = 0; q < 4; q++)
            b.j[4 + q] = {aggx + (size_t)co4[q] * 256, wpan_h(0, tdst[q]), wpan_l(0, tdst[q]),
                          x1 + (size_t)dbase4[q] * 256, nullptr, bconv + tdst[q] * 256, Nd4[q], 256, 1};
        gemm_mfma<<<dim3(320, 1, 8), 256, 0, stream>>>(b);
    }
    agg_ts<<<12500, 256, 0, stream>>>(attnT, attnC, hscbf, rowptr, ssrc, bconv, x1);

    // ---- layer 2 (ts outputs only, pooled via per-block partials) ----
    attnproj<<<329, 256, 0, stream>>>(x1, weff + 40960, attnT, attnC);
    {
        MBatch b = {};
        for (int q = 0; q < 4; q++)
            b.j[q] = {x1 + (size_t)dbase4[q] * 256, wpan_h(1, tsrc[q]), wpan_l(1, tsrc[q]),
                      nullptr, hscbf + (size_t)co4[q] * 256, nullptr, Nd4[q], 256, 0};
        gemm_mfma<<<dim3(320, 1, 4), 256, 0, stream>>>(b);
    }
    agg_ts_pool<<<12500, 256, 0, stream>>>(attnT, attnC, hscbf, rowptr, ssrc, bconv + 2048, part);
    hipMemsetAsync(gsum, 0, 256 * sizeof(float), stream);
    colsum_part<<<256, 256, 0, stream>>>(part, gsum);

    head_k<<<1, 128, 0, stream>>>(gsum, Wc1, bc1, Wc2, bc2, (float*)d_out);
}